// Round 17
// baseline (346.541 us; speedup 1.0000x reference)
//
#include <hip/hip_runtime.h>
#include <cstddef>

#define NROWS 16384
#define NCOLS 4096
#define NG 32
#define GD 128
#define NPC 16              // K-stripes (1024 samples each)

typedef float f32x4 __attribute__((ext_vector_type(4)));
typedef short bf16x8 __attribute__((ext_vector_type(8)));

__device__ inline unsigned short f2bf(float f) {
    unsigned int u = __builtin_bit_cast(unsigned int, f);
    u += 0x7fffu + ((u >> 16) & 1u);
    return (unsigned short)(u >> 16);
}

// ============ K1: fused load+transpose+bf16 MFMA partial X^T X + col sums =====
// R11 structure minus the xhi side-write. 512 thr / 8 waves; grid 512.
__global__ __launch_bounds__(512) void k_cov(
    const float* __restrict__ x, float* __restrict__ xtx, float* __restrict__ ps)
{
    __shared__ unsigned short xt[2][128][42];
    __shared__ float red[8][128];
    const int bid = blockIdx.x;
    const int g = bid >> 4, p = bid & 15;
    const int t = threadIdx.x;
    const int w = t >> 6;           // wave 0..7
    const int lane = t & 63;
    const int f2 = lane;            // feature pair 0..63
    const int lm = lane & 15, lk = lane >> 4;
    const float* xb = x + (size_t)(p * 1024) * NCOLS + g * GD + 2 * f2;

    float csum0 = 0.f, csum1 = 0.f;
    f32x4 acc[8];
#pragma unroll
    for (int ni = 0; ni < 8; ++ni) acc[ni] = (f32x4){0.f, 0.f, 0.f, 0.f};

    float2 v[4];
#define CLOAD(CC) \
    _Pragma("unroll") for (int i = 0; i < 4; ++i) \
        v[i] = *(const float2*)(xb + (size_t)((CC) * 32 + w * 4 + i) * NCOLS);
#define CWRITE(BUF) { \
    ushort4 h0, h1; \
    unsigned short* hp0 = (unsigned short*)&h0; \
    unsigned short* hp1 = (unsigned short*)&h1; \
    _Pragma("unroll") for (int i = 0; i < 4; ++i) { \
        csum0 += v[i].x; csum1 += v[i].y; \
        hp0[i] = f2bf(v[i].x); hp1[i] = f2bf(v[i].y); } \
    *(ushort4*)&xt[BUF][2 * f2][w * 4] = h0; \
    *(ushort4*)&xt[BUF][2 * f2 + 1][w * 4] = h1; }

    CLOAD(0);
    CWRITE(0);
    __syncthreads();

    for (int c = 0; c < 32; ++c) {
        const int cur = c & 1;
        if (c < 31) { CLOAD(c + 1); }
        bf16x8 A0 = *(const bf16x8*)&xt[cur][w * 16 + lm][lk * 8];
        bf16x8 B[8];
#pragma unroll
        for (int n = 0; n < 8; ++n)
            B[n] = *(const bf16x8*)&xt[cur][n * 16 + lm][lk * 8];
#pragma unroll
        for (int n = 0; n < 8; ++n)
            acc[n] = __builtin_amdgcn_mfma_f32_16x16x32_bf16(A0, B[n], acc[n], 0, 0, 0);
        if (c < 31) { CWRITE(cur ^ 1); }
        __syncthreads();
    }
#undef CLOAD
#undef CWRITE

    float* ob = xtx + (size_t)bid * (GD * GD);
#pragma unroll
    for (int ni = 0; ni < 8; ++ni) {
        const int i0 = w * 16 + lk * 4;
        const int j = ni * 16 + lm;
#pragma unroll
        for (int r = 0; r < 4; ++r)
            ob[(size_t)(i0 + r) * GD + j] = acc[ni][r];
    }
    red[w][2 * f2] = csum0;
    red[w][2 * f2 + 1] = csum1;
    __syncthreads();
    if (t < 128) {
        float s = 0.f;
#pragma unroll
        for (int r = 0; r < 8; ++r) s += red[r][t];
        ps[(size_t)bid * GD + t] = s;
    }
}

// ============ K2: reduce partials -> C (mean inlined from ps) =================
__global__ __launch_bounds__(256) void k_covreduce(
    const float* __restrict__ xtx, const float* __restrict__ ps,
    float* __restrict__ C)
{
    __shared__ float mu[128];
    const int bid = blockIdx.x;
    const int g = bid >> 4, s = bid & 15;
    const int t = threadIdx.x;
    if (t < 128) {
        float m = 0.f;
#pragma unroll
        for (int p = 0; p < NPC; ++p) m += ps[(size_t)(g * NPC + p) * GD + t];
        mu[t] = m * (1.0f / (float)NROWS);
    }
    __syncthreads();
    const int e = s * 1024 + t * 4;
    const int i = e >> 7, j = e & 127;
    float4 sum = make_float4(0.f, 0.f, 0.f, 0.f);
#pragma unroll
    for (int p = 0; p < NPC; ++p) {
        const float4 vv = *(const float4*)(xtx + ((size_t)(g * NPC + p) << 14) + e);
        sum.x += vv.x; sum.y += vv.y; sum.z += vv.z; sum.w += vv.w;
    }
    const float inv = 1.0f / (float)(NROWS - 1);
    const float mi2 = (float)NROWS * mu[i];
    float4 r;
    r.x = (sum.x - mi2 * mu[j + 0]) * inv;
    r.y = (sum.y - mi2 * mu[j + 1]) * inv;
    r.z = (sum.z - mi2 * mu[j + 2]) * inv;
    r.w = (sum.w - mi2 * mu[j + 3]) * inv;
    *(float4*)(C + (size_t)g * (GD * GD) + e) = r;
}

// ============ K3: Gershgorin scale + Y0/Z0 ====================================
__global__ __launch_bounds__(256) void k_prep(
    const float* __restrict__ Cg, float* __restrict__ scale,
    float* __restrict__ Y0, float* __restrict__ Z0)
{
    __shared__ float Cs[128][129];
    __shared__ float rs[128];
    __shared__ float sinv[1];
    const int g = blockIdx.x;
    const int t = threadIdx.x;
    for (int k = 0; k < 64; ++k) {
        int e = t + 256 * k;
        Cs[e >> 7][e & 127] = Cg[(size_t)g * (GD * GD) + e];
    }
    __syncthreads();
    if (t < 128) {
        float s = 0.f;
        for (int i = 0; i < 128; ++i) s += fabsf(Cs[i][t]);
        rs[t] = s;
    }
    __syncthreads();
    if (t == 0) {
        float up = 0.f, lo = 1e30f;
        for (int i = 0; i < 128; ++i) {
            up = fmaxf(up, rs[i]);
            lo = fminf(lo, 2.0f * Cs[i][i] - rs[i]);
        }
        float c = 0.5f * (up + fmaxf(lo, 0.0f));
        c = fmaxf(c, 1e-20f);
        sinv[0] = 1.0f / c;
        scale[g] = rsqrtf(c);
    }
    __syncthreads();
    const float invc = sinv[0];
    for (int k = 0; k < 64; ++k) {
        int e = t + 256 * k;
        int i = e >> 7, j = e & 127;
        Y0[(size_t)g * (GD * GD) + e] = Cs[i][j] * invc;
        Z0[(size_t)g * (GD * GD) + e] = (i == j) ? 1.0f : 0.0f;
    }
}

// ============ K4: Newton-Schulz iteration (fp32) ==============================
__global__ __launch_bounds__(256) void k_ns_iter(
    const float* __restrict__ Yin, const float* __restrict__ Zin,
    float* __restrict__ Yout, float* __restrict__ Zout)
{
    __shared__ float Ys[128][132];
    __shared__ float Zs[128][132];
    __shared__ float Ts[128][16];
    const int bid = blockIdx.x;
    const int g = bid >> 3;
    const int sl = bid & 7;
    const int J0 = sl * 16;
    const int t = threadIdx.x;
    const float* Yg = Yin + (size_t)g * GD * GD;
    const float* Zg = Zin + (size_t)g * GD * GD;
#pragma unroll
    for (int k = 0; k < 16; ++k) {
        int q = t + 256 * k;
        int row = q >> 5, c4 = q & 31;
        *(float4*)&Ys[row][c4 * 4] = *(const float4*)(Yg + (size_t)q * 4);
        *(float4*)&Zs[row][c4 * 4] = *(const float4*)(Zg + (size_t)q * 4);
    }
    __syncthreads();
    const int i = t >> 1;
    const int jb = (t & 1) * 8;

    float accT[8];
#pragma unroll
    for (int q = 0; q < 8; ++q) accT[q] = 0.f;
    for (int k4 = 0; k4 < 32; ++k4) {
        float4 zv = *(const float4*)&Zs[i][k4 * 4];
        float zz[4] = {zv.x, zv.y, zv.z, zv.w};
#pragma unroll
        for (int e = 0; e < 4; ++e) {
            const int k = k4 * 4 + e;
            float4 y0 = *(const float4*)&Ys[k][J0 + jb];
            float4 y1 = *(const float4*)&Ys[k][J0 + jb + 4];
            float yy[8] = {y0.x, y0.y, y0.z, y0.w, y1.x, y1.y, y1.z, y1.w};
#pragma unroll
            for (int q = 0; q < 8; ++q) accT[q] = fmaf(zz[e], yy[q], accT[q]);
        }
    }
#pragma unroll
    for (int q = 0; q < 8; ++q) Ts[i][jb + q] = accT[q];
    __syncthreads();

    float ay[8], az[8];
#pragma unroll
    for (int q = 0; q < 8; ++q) { ay[q] = 0.f; az[q] = 0.f; }
    for (int k4 = 0; k4 < 32; ++k4) {
        float4 yv = *(const float4*)&Ys[i][k4 * 4];
        float4 zv = *(const float4*)&Zs[i][k4 * 4];
        float yy[4] = {yv.x, yv.y, yv.z, yv.w};
        float zz[4] = {zv.x, zv.y, zv.z, zv.w};
#pragma unroll
        for (int e = 0; e < 4; ++e) {
            const int k = k4 * 4 + e;
            float4 t0 = *(const float4*)&Ts[k][jb];
            float4 t1 = *(const float4*)&Ts[k][jb + 4];
            float tt[8] = {t0.x, t0.y, t0.z, t0.w, t1.x, t1.y, t1.z, t1.w};
#pragma unroll
            for (int q = 0; q < 8; ++q) {
                ay[q] = fmaf(yy[e], tt[q], ay[q]);
                az[q] = fmaf(zz[e], tt[q], az[q]);
            }
        }
    }
    float4 yc0 = *(const float4*)&Ys[i][J0 + jb];
    float4 yc1 = *(const float4*)&Ys[i][J0 + jb + 4];
    float4 zc0 = *(const float4*)&Zs[i][J0 + jb];
    float4 zc1 = *(const float4*)&Zs[i][J0 + jb + 4];
    float* Yo = Yout + (size_t)g * GD * GD + (size_t)i * GD + J0 + jb;
    float* Zo = Zout + (size_t)g * GD * GD + (size_t)i * GD + J0 + jb;
    *(float4*)(Yo)     = make_float4(1.5f*yc0.x - 0.5f*ay[0], 1.5f*yc0.y - 0.5f*ay[1],
                                     1.5f*yc0.z - 0.5f*ay[2], 1.5f*yc0.w - 0.5f*ay[3]);
    *(float4*)(Yo + 4) = make_float4(1.5f*yc1.x - 0.5f*ay[4], 1.5f*yc1.y - 0.5f*ay[5],
                                     1.5f*yc1.z - 0.5f*ay[6], 1.5f*yc1.w - 0.5f*ay[7]);
    *(float4*)(Zo)     = make_float4(1.5f*zc0.x - 0.5f*az[0], 1.5f*zc0.y - 0.5f*az[1],
                                     1.5f*zc0.z - 0.5f*az[2], 1.5f*zc0.w - 0.5f*az[3]);
    *(float4*)(Zo + 4) = make_float4(1.5f*zc1.x - 0.5f*az[4], 1.5f*zc1.y - 0.5f*az[5],
                                     1.5f*zc1.z - 0.5f*az[6], 1.5f*zc1.w - 0.5f*az[7]);
}

// ============ K5: WT = (Z*rsqrt(c))^T bf16 ; muW = mu . W (mean inlined) ======
__global__ __launch_bounds__(256) void k_wprep(
    const float* __restrict__ Z, const float* __restrict__ scale,
    const float* __restrict__ ps,
    unsigned short* __restrict__ WT, float* __restrict__ muW)
{
    __shared__ float Zs[128][129];
    __shared__ float mu[128];
    const int g = blockIdx.x;
    const int t = threadIdx.x;
    const float sc = scale[g];
    if (t < 128) {
        float m = 0.f;
#pragma unroll
        for (int p = 0; p < NPC; ++p) m += ps[(size_t)(g * NPC + p) * GD + t];
        mu[t] = m * (1.0f / (float)NROWS);
    }
    for (int k = 0; k < 64; ++k) {
        int e = t + 256 * k;
        Zs[e >> 7][e & 127] = Z[(size_t)g * (GD * GD) + e];
    }
    __syncthreads();
    const int n = t & 127, kh = t >> 7;
    unsigned short* o = WT + (size_t)g * (GD * GD) + (size_t)n * GD + kh * 64;
    for (int k = 0; k < 64; k += 2) {
        unsigned int pk = (unsigned int)f2bf(Zs[kh * 64 + k][n] * sc)
                        | ((unsigned int)f2bf(Zs[kh * 64 + k + 1][n] * sc) << 16);
        *(unsigned int*)(o + k) = pk;
    }
    if (t < 128) {
        float s = 0.f;
        for (int d = 0; d < 128; ++d) s = fmaf(mu[d], Zs[d][t], s);
        muW[g * GD + t] = s * sc;
    }
}

// ============ K6: out = x*W - muW; fp32 reads, micro-block, LDS-bounce ========
// grid 16384 = 512 rb x 32 g (g low bits); 256 thr / 4 waves; straight-line:
// 32 rows x full 128-feature group; MFMA -> LDS -> 512 B-contiguous stores.
__global__ __launch_bounds__(256) void k_apply(
    const float* __restrict__ x, const unsigned short* __restrict__ WT,
    const float* __restrict__ muW, float* __restrict__ out)
{
    __shared__ float tile[32][132];
    const int bid = blockIdx.x;
    const int g = bid & 31;
    const int rb = bid >> 5;            // 0..511, 32 rows each
    const int t = threadIdx.x;
    const int lane = t & 63, w = t >> 6;
    const int lm = lane & 15, lk = lane >> 4;
    const int fq = w;                   // f-quarter (32 cols)

    bf16x8 Wf[2][4];
    {
        const unsigned short* wg = WT + (size_t)g * (GD * GD);
#pragma unroll
        for (int fi = 0; fi < 2; ++fi)
#pragma unroll
            for (int ks = 0; ks < 4; ++ks)
                Wf[fi][ks] = *(const bf16x8*)(wg
                    + (size_t)(fq * 32 + fi * 16 + lm) * GD + ks * 32 + lk * 8);
    }
    float mw[2];
#pragma unroll
    for (int fi = 0; fi < 2; ++fi)
        mw[fi] = muW[g * GD + fq * 32 + fi * 16 + lm];

    const int row0 = rb * 32;
    const float* ab = x + (size_t)(row0 + lm) * NCOLS + g * GD + lk * 8;

    // issue ALL 16 fp32 loads first (static indices)
    float4 u[16];
#pragma unroll
    for (int ks = 0; ks < 4; ++ks) {
        u[ks * 4 + 0] = *(const float4*)(ab + ks * 32);
        u[ks * 4 + 1] = *(const float4*)(ab + ks * 32 + 4);
        u[ks * 4 + 2] = *(const float4*)(ab + (size_t)16 * NCOLS + ks * 32);
        u[ks * 4 + 3] = *(const float4*)(ab + (size_t)16 * NCOLS + ks * 32 + 4);
    }

    f32x4 acc[2][2];
#pragma unroll
    for (int mi = 0; mi < 2; ++mi)
#pragma unroll
        for (int fi = 0; fi < 2; ++fi) acc[mi][fi] = (f32x4){0.f, 0.f, 0.f, 0.f};

#pragma unroll
    for (int ks = 0; ks < 4; ++ks) {
        float4 q0 = u[ks * 4 + 0], q1 = u[ks * 4 + 1];
        float4 q2 = u[ks * 4 + 2], q3 = u[ks * 4 + 3];
        bf16x8 a0, a1;
        a0[0] = (short)f2bf(q0.x); a0[1] = (short)f2bf(q0.y);
        a0[2] = (short)f2bf(q0.z); a0[3] = (short)f2bf(q0.w);
        a0[4] = (short)f2bf(q1.x); a0[5] = (short)f2bf(q1.y);
        a0[6] = (short)f2bf(q1.z); a0[7] = (short)f2bf(q1.w);
        a1[0] = (short)f2bf(q2.x); a1[1] = (short)f2bf(q2.y);
        a1[2] = (short)f2bf(q2.z); a1[3] = (short)f2bf(q2.w);
        a1[4] = (short)f2bf(q3.x); a1[5] = (short)f2bf(q3.y);
        a1[6] = (short)f2bf(q3.z); a1[7] = (short)f2bf(q3.w);
#pragma unroll
        for (int fi = 0; fi < 2; ++fi) {
            acc[0][fi] = __builtin_amdgcn_mfma_f32_16x16x32_bf16(
                a0, Wf[fi][ks], acc[0][fi], 0, 0, 0);
            acc[1][fi] = __builtin_amdgcn_mfma_f32_16x16x32_bf16(
                a1, Wf[fi][ks], acc[1][fi], 0, 0, 0);
        }
    }

    // MFMA layout -> LDS (disjoint fq columns per wave; 2-way aliasing = free)
#pragma unroll
    for (int mi = 0; mi < 2; ++mi)
#pragma unroll
        for (int fi = 0; fi < 2; ++fi)
#pragma unroll
            for (int r = 0; r < 4; ++r)
                tile[mi * 16 + lk * 4 + r][fq * 32 + fi * 16 + lm]
                    = acc[mi][fi][r] - mw[fi];
    __syncthreads();

    // cooperative sequential store: dwordx4, 512 B contiguous per row
    const int srow = t >> 5;            // 0..7
    const int scol = (t & 31) * 4;      // 0..124
    float* obase = out + (size_t)row0 * NCOLS + g * GD;
#pragma unroll
    for (int p = 0; p < 4; ++p) {
        const int row = p * 8 + srow;
        float4 vv = *(const float4*)&tile[row][scol];
        *(float4*)(obase + (size_t)row * NCOLS + scol) = vv;
    }
}

extern "C" void kernel_launch(void* const* d_in, const int* in_sizes, int n_in,
                              void* d_out, int out_size, void* d_ws, size_t ws_size,
                              hipStream_t stream) {
    const float* x = (const float*)d_in[0];
    float* out = (float*)d_out;
    float* ws = (float*)d_ws;

    float* xtx   = ws;                                    // 8,388,608 f
    float* ps    = xtx + (size_t)NG * NPC * GD * GD;      // 65,536 f
    float* scale = ps + (size_t)NG * NPC * GD;            // 32
    float* Cbuf  = scale + 32;                            // 524,288
    float* Ya    = Cbuf + (size_t)NG * GD * GD;
    float* Za    = Ya + (size_t)NG * GD * GD;
    float* Yb    = Za + (size_t)NG * GD * GD;
    float* Zb    = Yb + (size_t)NG * GD * GD;
    float* muW   = Zb + (size_t)NG * GD * GD;             // 4,096
    unsigned short* WT = (unsigned short*)(muW + NCOLS);  // 4 MB

    k_cov<<<NG * NPC, 512, 0, stream>>>(x, xtx, ps);
    k_covreduce<<<NG * NPC, 256, 0, stream>>>(xtx, ps, Cbuf);
    k_prep<<<NG, 256, 0, stream>>>(Cbuf, scale, Ya, Za);
    // 4 Newton-Schulz iterations (e0~0.18 -> e4 ~ 1e-13): final Z in Za
    for (int it = 0; it < 4; ++it) {
        if ((it & 1) == 0)
            k_ns_iter<<<NG * 8, 256, 0, stream>>>(Ya, Za, Yb, Zb);
        else
            k_ns_iter<<<NG * 8, 256, 0, stream>>>(Yb, Zb, Ya, Za);
    }
    k_wprep<<<NG, 256, 0, stream>>>(Za, scale, ps, WT, muW);
    k_apply<<<NG * 512, 256, 0, stream>>>(x, WT, muW, out);
}

// Round 18
// 309.878 us; speedup vs baseline: 1.1183x; 1.1183x over previous
//
#include <hip/hip_runtime.h>
#include <cstddef>

#define NROWS 16384
#define NCOLS 4096
#define NG 32
#define GD 128
#define NPC 16              // K-stripes (1024 samples each)

typedef float f32x4 __attribute__((ext_vector_type(4)));
typedef short bf16x8 __attribute__((ext_vector_type(8)));

__device__ inline unsigned short f2bf(float f) {
    unsigned int u = __builtin_bit_cast(unsigned int, f);
    u += 0x7fffu + ((u >> 16) & 1u);
    return (unsigned short)(u >> 16);
}

// ============ K1: fused load+transpose+bf16 MFMA partial X^T X + col sums =====
// R11/R15 exact version. 512 thr / 8 waves; emits bf16 copy xhi.
__global__ __launch_bounds__(512) void k_cov(
    const float* __restrict__ x, float* __restrict__ xtx, float* __restrict__ ps,
    unsigned short* __restrict__ xhi)
{
    __shared__ unsigned short xt[2][128][42];
    __shared__ float red[8][128];
    const int bid = blockIdx.x;
    const int g = bid >> 4, p = bid & 15;
    const int t = threadIdx.x;
    const int w = t >> 6;           // wave 0..7
    const int lane = t & 63;
    const int f2 = lane;            // feature pair 0..63
    const int lm = lane & 15, lk = lane >> 4;
    const float* xb = x + (size_t)(p * 1024) * NCOLS + g * GD + 2 * f2;
    unsigned int* xo = (unsigned int*)(xhi
        + ((size_t)g * NROWS + p * 1024 + w * 4) * GD + 2 * f2);

    float csum0 = 0.f, csum1 = 0.f;
    f32x4 acc[8];
#pragma unroll
    for (int ni = 0; ni < 8; ++ni) acc[ni] = (f32x4){0.f, 0.f, 0.f, 0.f};

    float2 v[4];
#define CLOAD(CC) \
    _Pragma("unroll") for (int i = 0; i < 4; ++i) \
        v[i] = *(const float2*)(xb + (size_t)((CC) * 32 + w * 4 + i) * NCOLS);
#define CWRITE(BUF, CC) { \
    ushort4 h0, h1; \
    unsigned short* hp0 = (unsigned short*)&h0; \
    unsigned short* hp1 = (unsigned short*)&h1; \
    _Pragma("unroll") for (int i = 0; i < 4; ++i) { \
        csum0 += v[i].x; csum1 += v[i].y; \
        unsigned int b0 = f2bf(v[i].x), b1 = f2bf(v[i].y); \
        hp0[i] = (unsigned short)b0; hp1[i] = (unsigned short)b1; \
        xo[(size_t)((CC) * 32 + i) * 64] = b0 | (b1 << 16); } \
    *(ushort4*)&xt[BUF][2 * f2][w * 4] = h0; \
    *(ushort4*)&xt[BUF][2 * f2 + 1][w * 4] = h1; }

    CLOAD(0);
    CWRITE(0, 0);
    __syncthreads();

    for (int c = 0; c < 32; ++c) {
        const int cur = c & 1;
        if (c < 31) { CLOAD(c + 1); }
        bf16x8 A0 = *(const bf16x8*)&xt[cur][w * 16 + lm][lk * 8];
        bf16x8 B[8];
#pragma unroll
        for (int n = 0; n < 8; ++n)
            B[n] = *(const bf16x8*)&xt[cur][n * 16 + lm][lk * 8];
#pragma unroll
        for (int n = 0; n < 8; ++n)
            acc[n] = __builtin_amdgcn_mfma_f32_16x16x32_bf16(A0, B[n], acc[n], 0, 0, 0);
        if (c < 31) { CWRITE(cur ^ 1, c + 1); }
        __syncthreads();
    }
#undef CLOAD
#undef CWRITE

    float* ob = xtx + (size_t)bid * (GD * GD);
#pragma unroll
    for (int ni = 0; ni < 8; ++ni) {
        const int i0 = w * 16 + lk * 4;
        const int j = ni * 16 + lm;
#pragma unroll
        for (int r = 0; r < 4; ++r)
            ob[(size_t)(i0 + r) * GD + j] = acc[ni][r];
    }
    red[w][2 * f2] = csum0;
    red[w][2 * f2 + 1] = csum1;
    __syncthreads();
    if (t < 128) {
        float s = 0.f;
#pragma unroll
        for (int r = 0; r < 8; ++r) s += red[r][t];
        ps[(size_t)bid * GD + t] = s;
    }
}

// ============ K2: reduce partials -> C (mean inlined from ps) =================
__global__ __launch_bounds__(256) void k_covreduce(
    const float* __restrict__ xtx, const float* __restrict__ ps,
    float* __restrict__ C)
{
    __shared__ float mu[128];
    const int bid = blockIdx.x;
    const int g = bid >> 4, s = bid & 15;
    const int t = threadIdx.x;
    if (t < 128) {
        float m = 0.f;
#pragma unroll
        for (int p = 0; p < NPC; ++p) m += ps[(size_t)(g * NPC + p) * GD + t];
        mu[t] = m * (1.0f / (float)NROWS);
    }
    __syncthreads();
    const int e = s * 1024 + t * 4;
    const int i = e >> 7, j = e & 127;
    float4 sum = make_float4(0.f, 0.f, 0.f, 0.f);
#pragma unroll
    for (int p = 0; p < NPC; ++p) {
        const float4 vv = *(const float4*)(xtx + ((size_t)(g * NPC + p) << 14) + e);
        sum.x += vv.x; sum.y += vv.y; sum.z += vv.z; sum.w += vv.w;
    }
    const float inv = 1.0f / (float)(NROWS - 1);
    const float mi2 = (float)NROWS * mu[i];
    float4 r;
    r.x = (sum.x - mi2 * mu[j + 0]) * inv;
    r.y = (sum.y - mi2 * mu[j + 1]) * inv;
    r.z = (sum.z - mi2 * mu[j + 2]) * inv;
    r.w = (sum.w - mi2 * mu[j + 3]) * inv;
    *(float4*)(C + (size_t)g * (GD * GD) + e) = r;
}

// ============ K3: Gershgorin scale + Y0/Z0 ====================================
__global__ __launch_bounds__(256) void k_prep(
    const float* __restrict__ Cg, float* __restrict__ scale,
    float* __restrict__ Y0, float* __restrict__ Z0)
{
    __shared__ float Cs[128][129];
    __shared__ float rs[128];
    __shared__ float sinv[1];
    const int g = blockIdx.x;
    const int t = threadIdx.x;
    for (int k = 0; k < 64; ++k) {
        int e = t + 256 * k;
        Cs[e >> 7][e & 127] = Cg[(size_t)g * (GD * GD) + e];
    }
    __syncthreads();
    if (t < 128) {
        float s = 0.f;
        for (int i = 0; i < 128; ++i) s += fabsf(Cs[i][t]);
        rs[t] = s;
    }
    __syncthreads();
    if (t == 0) {
        float up = 0.f, lo = 1e30f;
        for (int i = 0; i < 128; ++i) {
            up = fmaxf(up, rs[i]);
            lo = fminf(lo, 2.0f * Cs[i][i] - rs[i]);
        }
        float c = 0.5f * (up + fmaxf(lo, 0.0f));
        c = fmaxf(c, 1e-20f);
        sinv[0] = 1.0f / c;
        scale[g] = rsqrtf(c);
    }
    __syncthreads();
    const float invc = sinv[0];
    for (int k = 0; k < 64; ++k) {
        int e = t + 256 * k;
        int i = e >> 7, j = e & 127;
        Y0[(size_t)g * (GD * GD) + e] = Cs[i][j] * invc;
        Z0[(size_t)g * (GD * GD) + e] = (i == j) ? 1.0f : 0.0f;
    }
}

// ============ K4: Newton-Schulz iteration (fp32) ==============================
__global__ __launch_bounds__(256) void k_ns_iter(
    const float* __restrict__ Yin, const float* __restrict__ Zin,
    float* __restrict__ Yout, float* __restrict__ Zout)
{
    __shared__ float Ys[128][132];
    __shared__ float Zs[128][132];
    __shared__ float Ts[128][16];
    const int bid = blockIdx.x;
    const int g = bid >> 3;
    const int sl = bid & 7;
    const int J0 = sl * 16;
    const int t = threadIdx.x;
    const float* Yg = Yin + (size_t)g * GD * GD;
    const float* Zg = Zin + (size_t)g * GD * GD;
#pragma unroll
    for (int k = 0; k < 16; ++k) {
        int q = t + 256 * k;
        int row = q >> 5, c4 = q & 31;
        *(float4*)&Ys[row][c4 * 4] = *(const float4*)(Yg + (size_t)q * 4);
        *(float4*)&Zs[row][c4 * 4] = *(const float4*)(Zg + (size_t)q * 4);
    }
    __syncthreads();
    const int i = t >> 1;
    const int jb = (t & 1) * 8;

    float accT[8];
#pragma unroll
    for (int q = 0; q < 8; ++q) accT[q] = 0.f;
    for (int k4 = 0; k4 < 32; ++k4) {
        float4 zv = *(const float4*)&Zs[i][k4 * 4];
        float zz[4] = {zv.x, zv.y, zv.z, zv.w};
#pragma unroll
        for (int e = 0; e < 4; ++e) {
            const int k = k4 * 4 + e;
            float4 y0 = *(const float4*)&Ys[k][J0 + jb];
            float4 y1 = *(const float4*)&Ys[k][J0 + jb + 4];
            float yy[8] = {y0.x, y0.y, y0.z, y0.w, y1.x, y1.y, y1.z, y1.w};
#pragma unroll
            for (int q = 0; q < 8; ++q) accT[q] = fmaf(zz[e], yy[q], accT[q]);
        }
    }
#pragma unroll
    for (int q = 0; q < 8; ++q) Ts[i][jb + q] = accT[q];
    __syncthreads();

    float ay[8], az[8];
#pragma unroll
    for (int q = 0; q < 8; ++q) { ay[q] = 0.f; az[q] = 0.f; }
    for (int k4 = 0; k4 < 32; ++k4) {
        float4 yv = *(const float4*)&Ys[i][k4 * 4];
        float4 zv = *(const float4*)&Zs[i][k4 * 4];
        float yy[4] = {yv.x, yv.y, yv.z, yv.w};
        float zz[4] = {zv.x, zv.y, zv.z, zv.w};
#pragma unroll
        for (int e = 0; e < 4; ++e) {
            const int k = k4 * 4 + e;
            float4 t0 = *(const float4*)&Ts[k][jb];
            float4 t1 = *(const float4*)&Ts[k][jb + 4];
            float tt[8] = {t0.x, t0.y, t0.z, t0.w, t1.x, t1.y, t1.z, t1.w};
#pragma unroll
            for (int q = 0; q < 8; ++q) {
                ay[q] = fmaf(yy[e], tt[q], ay[q]);
                az[q] = fmaf(zz[e], tt[q], az[q]);
            }
        }
    }
    float4 yc0 = *(const float4*)&Ys[i][J0 + jb];
    float4 yc1 = *(const float4*)&Ys[i][J0 + jb + 4];
    float4 zc0 = *(const float4*)&Zs[i][J0 + jb];
    float4 zc1 = *(const float4*)&Zs[i][J0 + jb + 4];
    float* Yo = Yout + (size_t)g * GD * GD + (size_t)i * GD + J0 + jb;
    float* Zo = Zout + (size_t)g * GD * GD + (size_t)i * GD + J0 + jb;
    *(float4*)(Yo)     = make_float4(1.5f*yc0.x - 0.5f*ay[0], 1.5f*yc0.y - 0.5f*ay[1],
                                     1.5f*yc0.z - 0.5f*ay[2], 1.5f*yc0.w - 0.5f*ay[3]);
    *(float4*)(Yo + 4) = make_float4(1.5f*yc1.x - 0.5f*ay[4], 1.5f*yc1.y - 0.5f*ay[5],
                                     1.5f*yc1.z - 0.5f*ay[6], 1.5f*yc1.w - 0.5f*ay[7]);
    *(float4*)(Zo)     = make_float4(1.5f*zc0.x - 0.5f*az[0], 1.5f*zc0.y - 0.5f*az[1],
                                     1.5f*zc0.z - 0.5f*az[2], 1.5f*zc0.w - 0.5f*az[3]);
    *(float4*)(Zo + 4) = make_float4(1.5f*zc1.x - 0.5f*az[4], 1.5f*zc1.y - 0.5f*az[5],
                                     1.5f*zc1.z - 0.5f*az[6], 1.5f*zc1.w - 0.5f*az[7]);
}

// ============ K5: WT = (Z*rsqrt(c))^T bf16 ; muW = mu . W (mean inlined) ======
__global__ __launch_bounds__(256) void k_wprep(
    const float* __restrict__ Z, const float* __restrict__ scale,
    const float* __restrict__ ps,
    unsigned short* __restrict__ WT, float* __restrict__ muW)
{
    __shared__ float Zs[128][129];
    __shared__ float mu[128];
    const int g = blockIdx.x;
    const int t = threadIdx.x;
    const float sc = scale[g];
    if (t < 128) {
        float m = 0.f;
#pragma unroll
        for (int p = 0; p < NPC; ++p) m += ps[(size_t)(g * NPC + p) * GD + t];
        mu[t] = m * (1.0f / (float)NROWS);
    }
    for (int k = 0; k < 64; ++k) {
        int e = t + 256 * k;
        Zs[e >> 7][e & 127] = Z[(size_t)g * (GD * GD) + e];
    }
    __syncthreads();
    const int n = t & 127, kh = t >> 7;
    unsigned short* o = WT + (size_t)g * (GD * GD) + (size_t)n * GD + kh * 64;
    for (int k = 0; k < 64; k += 2) {
        unsigned int pk = (unsigned int)f2bf(Zs[kh * 64 + k][n] * sc)
                        | ((unsigned int)f2bf(Zs[kh * 64 + k + 1][n] * sc) << 16);
        *(unsigned int*)(o + k) = pk;
    }
    if (t < 128) {
        float s = 0.f;
        for (int d = 0; d < 128; ++d) s = fmaf(mu[d], Zs[d][t], s);
        muW[g * GD + t] = s * sc;
    }
}

// ============ K6: out = xhi*W - muW; LDS-bounce epilogue (R15 exact) ==========
// grid 2048 = 32 g x 64 rbo; 512 thr / 8 waves; 4 chunks x 64 rows.
__global__ __launch_bounds__(512) void k_apply(
    const unsigned short* __restrict__ xhi, const unsigned short* __restrict__ WT,
    const float* __restrict__ muW, float* __restrict__ out)
{
    __shared__ float tile[64][132];
    const int bid = blockIdx.x;
    const int g = bid >> 6, rbo = bid & 63;
    const int t = threadIdx.x;
    const int lane = t & 63, w = t >> 6;
    const int lm = lane & 15, lk = lane >> 4;
    const int fq = w >> 1;              // f-quarter (32 cols)
    const int sh = (w & 1) * 32;        // sample offset within 64-row chunk

    bf16x8 Wf[2][4];
    {
        const unsigned short* wg = WT + (size_t)g * (GD * GD);
#pragma unroll
        for (int fi = 0; fi < 2; ++fi)
#pragma unroll
            for (int ks = 0; ks < 4; ++ks)
                Wf[fi][ks] = *(const bf16x8*)(wg
                    + (size_t)(fq * 32 + fi * 16 + lm) * GD + ks * 32 + lk * 8);
    }
    float mw[2];
#pragma unroll
    for (int fi = 0; fi < 2; ++fi)
        mw[fi] = muW[g * GD + fq * 32 + fi * 16 + lm];

    const int srow = t >> 5;            // 0..15: cooperative-store row base
    const int scol = (t & 31) * 4;      // 0..124: dword4 column

    for (int c = 0; c < 4; ++c) {
        const int row0 = rbo * 256 + c * 64;
        const unsigned short* ab = xhi
            + ((size_t)g * NROWS + row0 + sh + lm) * GD + lk * 8;

        bf16x8 u[8];
#pragma unroll
        for (int ks = 0; ks < 4; ++ks) {
            u[ks * 2 + 0] = *(const bf16x8*)(ab + ks * 32);
            u[ks * 2 + 1] = *(const bf16x8*)(ab + (size_t)16 * GD + ks * 32);
        }

        f32x4 acc[2][2];
#pragma unroll
        for (int mi = 0; mi < 2; ++mi)
#pragma unroll
            for (int fi = 0; fi < 2; ++fi) acc[mi][fi] = (f32x4){0.f, 0.f, 0.f, 0.f};

#pragma unroll
        for (int ks = 0; ks < 4; ++ks) {
#pragma unroll
            for (int fi = 0; fi < 2; ++fi) {
                acc[0][fi] = __builtin_amdgcn_mfma_f32_16x16x32_bf16(
                    u[ks * 2 + 0], Wf[fi][ks], acc[0][fi], 0, 0, 0);
                acc[1][fi] = __builtin_amdgcn_mfma_f32_16x16x32_bf16(
                    u[ks * 2 + 1], Wf[fi][ks], acc[1][fi], 0, 0, 0);
            }
        }

        // MFMA layout -> LDS (2-way bank aliasing only = free)
#pragma unroll
        for (int mi = 0; mi < 2; ++mi)
#pragma unroll
            for (int fi = 0; fi < 2; ++fi)
#pragma unroll
                for (int r = 0; r < 4; ++r)
                    tile[sh + mi * 16 + lk * 4 + r][fq * 32 + fi * 16 + lm]
                        = acc[mi][fi][r] - mw[fi];
        __syncthreads();

        // cooperative sequential store: dwordx4, 512 B contiguous per row
        float* obase = out + (size_t)row0 * NCOLS + g * GD;
#pragma unroll
        for (int p = 0; p < 4; ++p) {
            const int row = p * 16 + srow;
            float4 v = *(const float4*)&tile[row][scol];
            *(float4*)(obase + (size_t)row * NCOLS + scol) = v;
        }
        __syncthreads();
    }
}

extern "C" void kernel_launch(void* const* d_in, const int* in_sizes, int n_in,
                              void* d_out, int out_size, void* d_ws, size_t ws_size,
                              hipStream_t stream) {
    const float* x = (const float*)d_in[0];
    float* out = (float*)d_out;
    float* ws = (float*)d_ws;

    float* xtx   = ws;                                    // 8,388,608 f
    float* ps    = xtx + (size_t)NG * NPC * GD * GD;      // 65,536 f
    float* scale = ps + (size_t)NG * NPC * GD;            // 32
    float* Cbuf  = scale + 32;                            // 524,288
    float* Ya    = Cbuf + (size_t)NG * GD * GD;
    float* Za    = Ya + (size_t)NG * GD * GD;
    float* Yb    = Za + (size_t)NG * GD * GD;
    float* Zb    = Yb + (size_t)NG * GD * GD;
    float* muW   = Zb + (size_t)NG * GD * GD;             // 4,096
    unsigned short* WT  = (unsigned short*)(muW + NCOLS); // 4 MB
    unsigned short* xhi = WT + (size_t)NG * GD * GD;      // 128 MB

    k_cov<<<NG * NPC, 512, 0, stream>>>(x, xtx, ps, xhi);
    k_covreduce<<<NG * NPC, 256, 0, stream>>>(xtx, ps, Cbuf);
    k_prep<<<NG, 256, 0, stream>>>(Cbuf, scale, Ya, Za);
    // 4 Newton-Schulz iterations (HW-verified in R17, absmax unchanged):
    // final Z in Za
    for (int it = 0; it < 4; ++it) {
        if ((it & 1) == 0)
            k_ns_iter<<<NG * 8, 256, 0, stream>>>(Ya, Za, Yb, Zb);
        else
            k_ns_iter<<<NG * 8, 256, 0, stream>>>(Yb, Zb, Ya, Za);
    }
    k_wprep<<<NG, 256, 0, stream>>>(Za, scale, ps, WT, muW);
    k_apply<<<NG * 64, 512, 0, stream>>>(xhi, WT, muW, out);
}